// Round 5
// baseline (348.955 us; speedup 1.0000x reference)
//
#include <hip/hip_runtime.h>
#include <hip/hip_bf16.h>

// Problem constants
#define BB   4096
#define INW  1024
#define HH   1024
#define KIN  2048      // IN + H
#define NG   5120      // 3H + 2H
#define KH   32        // inner hidden

typedef __bf16 bf16;
typedef __bf16 bf16x4 __attribute__((ext_vector_type(4)));
typedef __bf16 bf16x8 __attribute__((ext_vector_type(8)));
typedef float  floatx4 __attribute__((ext_vector_type(4)));

#define GLD16(gp, lp)                                                          \
  __builtin_amdgcn_global_load_lds(                                            \
      (__attribute__((address_space(1))) const void*)(gp),                     \
      (__attribute__((address_space(3))) void*)(lp), 16, 0, 0)

// ---------------------------------------------------------------------------
// 1. prep: concat+cast x|h_prev -> comb bf16, and cast Wg,Wc -> Wb bf16
// ---------------------------------------------------------------------------
#define NC4  (BB * KIN / 4)        // float4 groups for comb
#define NWG4 (3 * HH * KIN / 4)    // for Wg
#define NWC4 (2 * HH * KIN / 4)    // for Wc

__global__ __launch_bounds__(256) void prep(
    const float* __restrict__ x, const float* __restrict__ h,
    const float* __restrict__ Wg, const float* __restrict__ Wc,
    bf16* __restrict__ comb, bf16* __restrict__ Wb) {
  int i = blockIdx.x * 256 + threadIdx.x;   // one float4 group
  const float* src;
  bf16* dst;
  if (i < NC4) {
    int e = i * 4;
    int b = e >> 11;          // / KIN
    int c = e & (KIN - 1);
    src = (c < INW) ? (x + (size_t)b * INW + c) : (h + (size_t)b * HH + (c - INW));
    dst = comb + e;
  } else if (i < NC4 + NWG4) {
    int e = (i - NC4) * 4;
    src = Wg + e;
    dst = Wb + e;
  } else {
    int e = (i - NC4 - NWG4) * 4;
    src = Wc + e;
    dst = Wb + (size_t)3 * HH * KIN + e;
  }
  float4 v = *(const float4*)src;
  bf16x4 o;
  o[0] = (bf16)v.x; o[1] = (bf16)v.y; o[2] = (bf16)v.z; o[3] = (bf16)v.w;
  *(bf16x4*)dst = o;
}

// ---------------------------------------------------------------------------
// 2. GEMM: G[M,N] = A[M,K] * Bm[N,K]^T   (M=4096, N=5120, K=2048), bf16 out.
//    R5: flatmm-style K-loop restructure. A staged in LDS (global_load_lds
//    width-16, XOR chunk swizzle, conflict-free); B fragments read DIRECTLY
//    from global each k-step — they are not ordered by __syncthreads, so
//    they overlap MFMA across the barrier (the overlap the 2-barrier m97
//    structure cannot express for staged operands). Barrier-drained staging
//    bytes halved (32KB -> 16KB per K-tile). Natural raster: consecutive
//    blockIdx.x share n0 -> 0.5 MB B slice stays L2-hot (32x reuse).
//    __launch_bounds__(256,3): pin 3 blocks/CU (R3 lesson: occupancy first).
// ---------------------------------------------------------------------------
__global__ __launch_bounds__(256, 3) void gemm_bt(
    const bf16* __restrict__ A, const bf16* __restrict__ Bm,
    bf16* __restrict__ C) {
  __shared__ bf16 As[128 * 64];   // 16 KB

  const int tid  = threadIdx.x;
  const int wave = tid >> 6;
  const int lane = tid & 63;
  const int m0 = blockIdx.x * 128;
  const int n0 = blockIdx.y * 128;

  const int wm = (wave >> 1) * 64;   // wave row origin in tile
  const int wn = (wave & 1) * 64;    // wave col origin in tile
  const int lr = lane & 15;          // row within 16x16 fragment
  const int qd = lane >> 4;          // k-chunk quad index (0..3)
  const int sw = lr & 7;             // A read-side swizzle key (row&7 == lr&7)

  floatx4 acc[4][4] = {};

  // Per-thread B fragment base pointers (row-major [N,K], k-offset qd*8)
  const bf16* Bp[4];
#pragma unroll
  for (int ni = 0; ni < 4; ++ni)
    Bp[ni] = Bm + (size_t)(n0 + wn + ni * 16 + lr) * KIN + qd * 8;

  for (int kt = 0; kt < KIN / 64; ++kt) {
    const int k0 = kt * 64;
    __syncthreads();  // previous iter's LDS reads must finish before overwrite
#pragma unroll
    for (int j = 0; j < 4; ++j) {
      int q   = j * 256 + tid;            // 1024 16B slots for the A tile
      int row = q >> 3;
      int c   = (q & 7) ^ (row & 7);      // XOR swizzle
      GLD16(A + (size_t)(m0 + row) * KIN + k0 + c * 8,
            As + (size_t)(j * 256 + wave * 64) * 8);
    }
    __syncthreads();

#pragma unroll
    for (int ks = 0; ks < 2; ++ks) {
      // B fragments straight from global (L2-resident slice)
      bf16x8 bfr[4];
#pragma unroll
      for (int ni = 0; ni < 4; ++ni)
        bfr[ni] = *(const bf16x8*)(Bp[ni] + k0 + ks * 32);
      // A fragments from LDS (swizzled)
      bf16x8 af[4];
#pragma unroll
      for (int mi = 0; mi < 4; ++mi)
        af[mi] = *(const bf16x8*)
            &As[(((wm + mi * 16 + lr) << 3) + ((ks * 4 + qd) ^ sw)) << 3];
#pragma unroll
      for (int mi = 0; mi < 4; ++mi)
#pragma unroll
        for (int ni = 0; ni < 4; ++ni)
          acc[mi][ni] = __builtin_amdgcn_mfma_f32_16x16x32_bf16(
              af[mi], bfr[ni], acc[mi][ni], 0, 0, 0);
    }
  }

  // Epilogue: C/D layout col = lane&15, row = (lane>>4)*4 + reg. bf16 store.
#pragma unroll
  for (int mi = 0; mi < 4; ++mi)
#pragma unroll
    for (int ni = 0; ni < 4; ++ni) {
      size_t base = (size_t)(m0 + wm + mi * 16 + qd * 4) * NG
                    + (n0 + wn + ni * 16 + lr);
#pragma unroll
      for (int r = 0; r < 4; ++r)
        C[base + (size_t)r * NG] = (bf16)acc[mi][ni][r];
    }
}

// ---------------------------------------------------------------------------
// 3. Fused epilogue: gates + inner MLP + cell update (reads bf16 G)
// ---------------------------------------------------------------------------
__global__ __launch_bounds__(256) void epilogue(
    const bf16* __restrict__ G, const float* __restrict__ c_prev,
    const float* __restrict__ bg, const float* __restrict__ bc,
    const float* __restrict__ W1, const float* __restrict__ b1,
    const float* __restrict__ W2, const float* __restrict__ b2,
    float* __restrict__ h_next, float* __restrict__ c_next) {
  int idx = blockIdx.x * 256 + threadIdx.x;   // one per (b,h)
  int b = idx >> 10;
  int h = idx & (HH - 1);
  const bf16* Gr = G + (size_t)b * NG;

  float gi = (float)Gr[h]          + bg[h];
  float gf = (float)Gr[HH + h]     + bg[HH + h];
  float go = (float)Gr[2 * HH + h] + bg[2 * HH + h];
  float p0 = (float)Gr[3 * HH + 2 * h]     + bc[2 * h];
  float p1 = (float)Gr[3 * HH + 2 * h + 1] + bc[2 * h + 1];

  float g = b2[0];
#pragma unroll
  for (int k = 0; k < KH; ++k) {
    float hv = fmaf(p0, W1[2 * k], fmaf(p1, W1[2 * k + 1], b1[k]));
    hv = fmaxf(hv, 0.0f);
    g = fmaf(hv, W2[k], g);
  }

  float si = 1.0f / (1.0f + __expf(-gi));
  float sf = 1.0f / (1.0f + __expf(-gf));
  float so = 1.0f / (1.0f + __expf(-go));

  float cn = sf * c_prev[idx] + si * g;
  float hn = so * tanhf(cn);
  h_next[idx] = hn;
  c_next[idx] = cn;
}

// ---------------------------------------------------------------------------
extern "C" void kernel_launch(void* const* d_in, const int* in_sizes, int n_in,
                              void* d_out, int out_size, void* d_ws, size_t ws_size,
                              hipStream_t stream) {
  const float* x      = (const float*)d_in[0];
  const float* h_prev = (const float*)d_in[1];
  const float* c_prev = (const float*)d_in[2];
  const float* Wg     = (const float*)d_in[3];
  const float* bg     = (const float*)d_in[4];
  const float* Wc     = (const float*)d_in[5];
  const float* bc     = (const float*)d_in[6];
  const float* W1     = (const float*)d_in[7];
  const float* b1     = (const float*)d_in[8];
  const float* W2     = (const float*)d_in[9];
  const float* b2     = (const float*)d_in[10];
  float* out = (float*)d_out;

  // workspace layout
  char* ws = (char*)d_ws;
  bf16* comb = (bf16*)ws;                                    // 16 MB
  bf16* Wb   = (bf16*)(ws + (size_t)BB * KIN * 2);           // 20 MB
  bf16* G    = (bf16*)(ws + (size_t)BB * KIN * 2
                          + (size_t)NG * KIN * 2);           // 40 MB

  // 1. prep (concat + casts, one kernel)
  prep<<<(NC4 + NWG4 + NWC4) / 256, 256, 0, stream>>>(x, h_prev, Wg, Wc, comb, Wb);

  // 2. GEMM: plain 2D raster (x = m-tiles fastest; blocks sharing y share B slice)
  dim3 grid(BB / 128, NG / 128);
  gemm_bt<<<grid, 256, 0, stream>>>(comb, Wb, G);

  // 3. epilogue
  epilogue<<<(BB * HH) / 256, 256, 0, stream>>>(
      G, c_prev, bg, bc, W1, b1, W2, b2, out, out + (size_t)BB * HH);
}

// Round 6
// 254.272 us; speedup vs baseline: 1.3724x; 1.3724x over previous
//
#include <hip/hip_runtime.h>
#include <hip/hip_bf16.h>

// Problem constants
#define BB   4096
#define INW  1024
#define HH   1024
#define KIN  2048      // IN + H
#define NG   5120      // 3H + 2H
#define KH   32        // inner hidden

typedef __bf16 bf16;
typedef __bf16 bf16x4 __attribute__((ext_vector_type(4)));
typedef __bf16 bf16x8 __attribute__((ext_vector_type(8)));
typedef float  floatx4 __attribute__((ext_vector_type(4)));

#define GLD16(gp, lp)                                                          \
  __builtin_amdgcn_global_load_lds(                                            \
      (__attribute__((address_space(1))) const void*)(gp),                     \
      (__attribute__((address_space(3))) void*)(lp), 16, 0, 0)

// ---------------------------------------------------------------------------
// 1. prep: concat+cast x|h_prev -> comb bf16, and shuffle-cast Wg,Wc -> Wb in
//    MFMA B-fragment order. 16B chunk id o = [nt][kk][f][lane] holds
//    B[n = nt*128 + f*16 + (lane&15)][k = kk*32 + (lane>>4)*8 .. +7], so the
//    GEMM's B-fragment load is base + lane*16 — perfectly coalesced.
// ---------------------------------------------------------------------------
#define NC4  (BB * KIN / 4)        // float4 groups for comb      (2,097,152)
#define NW8  (NG * KIN / 8)        // 16B output chunks for Wb    (1,310,720)

__global__ __launch_bounds__(256) void prep(
    const float* __restrict__ x, const float* __restrict__ h,
    const float* __restrict__ Wg, const float* __restrict__ Wc,
    bf16* __restrict__ comb, bf16* __restrict__ Wb) {
  int i = blockIdx.x * 256 + threadIdx.x;
  if (i < NC4) {                       // ---- comb: concat + cast ----
    int e = i * 4;
    int b = e >> 11;          // / KIN
    int c = e & (KIN - 1);
    const float* src = (c < INW) ? (x + (size_t)b * INW + c)
                                 : (h + (size_t)b * HH + (c - INW));
    float4 v = *(const float4*)src;
    bf16x4 o4;
    o4[0] = (bf16)v.x; o4[1] = (bf16)v.y; o4[2] = (bf16)v.z; o4[3] = (bf16)v.w;
    *(bf16x4*)(comb + e) = o4;
  } else {                             // ---- Wb: fragment-order shuffle ----
    int o = i - NC4;
    if (o < NW8) {
      int lane = o & 63;
      int f    = (o >> 6) & 7;
      int kk   = (o >> 9) & 63;
      int nt   = o >> 15;
      int n = nt * 128 + f * 16 + (lane & 15);
      int k = kk * 32 + (lane >> 4) * 8;
      const float* src = (n < 3 * HH) ? (Wg + (size_t)n * KIN + k)
                                      : (Wc + (size_t)(n - 3 * HH) * KIN + k);
      float4 v0 = *(const float4*)src;
      float4 v1 = *(const float4*)(src + 4);
      bf16x8 ov;
      ov[0] = (bf16)v0.x; ov[1] = (bf16)v0.y; ov[2] = (bf16)v0.z; ov[3] = (bf16)v0.w;
      ov[4] = (bf16)v1.x; ov[5] = (bf16)v1.y; ov[6] = (bf16)v1.z; ov[7] = (bf16)v1.w;
      *(bf16x8*)(Wb + (size_t)o * 8) = ov;
    }
  }
}

// ---------------------------------------------------------------------------
// 2. GEMM: G[M,N] = A[M,K] * B[N,K]^T, B pre-shuffled to fragment order.
//    R6 flatmm: A staged in LDS (R2's proven XOR-swizzle global_load_lds
//    path, 0 conflicts); B fragments loaded coalesced (lane*16B) from the
//    shuffled layout, ISSUED BEFORE the staging barriers so the compiler's
//    vmcnt(0) drain before s_barrier hides their latency behind A staging.
//    ds_read traffic and barrier-drained staging bytes both halved vs R2.
// ---------------------------------------------------------------------------
__global__ __launch_bounds__(256, 3) void gemm_bt(
    const bf16* __restrict__ A, const bf16* __restrict__ Bm,
    bf16* __restrict__ C) {
  __shared__ bf16 As[128 * 64];   // 16 KB

  const int tid  = threadIdx.x;
  const int wave = tid >> 6;
  const int lane = tid & 63;
  const int m0 = blockIdx.x * 128;
  const int nt = blockIdx.y;

  const int wm = (wave >> 1) * 64;   // wave row origin in tile
  const int wn = (wave & 1) * 64;    // wave col origin in tile
  const int lr = lane & 15;          // row within 16x16 fragment
  const int qd = lane >> 4;          // k-chunk quad index (0..3)
  const int sw = lr & 7;             // A read-side swizzle key

  // B base for this wave/lane in fragment-order layout:
  // chunk = ((nt*64 + kk)*8 + f)*64 + lane, f = (wave&1)*4 + ni
  const bf16* Bq = Bm + (size_t)nt * (64 * 8 * 64 * 8)
                      + (size_t)((wave & 1) * 4) * 512 + (size_t)lane * 8;

  floatx4 acc[4][4] = {};

  for (int kt = 0; kt < KIN / 64; ++kt) {
    const int k0 = kt * 64;

    // B fragment loads for this K-tile — issued BEFORE the barriers so the
    // pre-barrier vmcnt(0) drain covers them alongside the A staging.
    bf16x8 bfr[2][4];
#pragma unroll
    for (int ks = 0; ks < 2; ++ks)
#pragma unroll
      for (int ni = 0; ni < 4; ++ni)
        bfr[ks][ni] = *(const bf16x8*)(Bq + (((kt * 2 + ks) * 8 + ni) << 9));

    __syncthreads();  // previous iter's LDS reads must finish before overwrite
#pragma unroll
    for (int j = 0; j < 4; ++j) {
      int q   = j * 256 + tid;            // 1024 16B slots for the A tile
      int row = q >> 3;
      int c   = (q & 7) ^ (row & 7);      // XOR swizzle
      GLD16(A + (size_t)(m0 + row) * KIN + k0 + c * 8,
            As + (size_t)(j * 256 + wave * 64) * 8);
    }
    __syncthreads();

#pragma unroll
    for (int ks = 0; ks < 2; ++ks) {
      bf16x8 af[4];
#pragma unroll
      for (int mi = 0; mi < 4; ++mi)
        af[mi] = *(const bf16x8*)
            &As[(((wm + mi * 16 + lr) << 3) + ((ks * 4 + qd) ^ sw)) << 3];
#pragma unroll
      for (int mi = 0; mi < 4; ++mi)
#pragma unroll
        for (int ni = 0; ni < 4; ++ni)
          acc[mi][ni] = __builtin_amdgcn_mfma_f32_16x16x32_bf16(
              af[mi], bfr[ks][ni], acc[mi][ni], 0, 0, 0);
    }
  }

  // Epilogue: C/D layout col = lane&15, row = (lane>>4)*4 + reg. bf16 store.
#pragma unroll
  for (int mi = 0; mi < 4; ++mi)
#pragma unroll
    for (int ni = 0; ni < 4; ++ni) {
      size_t base = (size_t)(m0 + wm + mi * 16 + qd * 4) * NG
                    + ((size_t)nt * 128 + wn + ni * 16 + lr);
#pragma unroll
      for (int r = 0; r < 4; ++r)
        C[base + (size_t)r * NG] = (bf16)acc[mi][ni][r];
    }
}

// ---------------------------------------------------------------------------
// 3. Fused epilogue: gates + inner MLP + cell update (reads bf16 G)
// ---------------------------------------------------------------------------
__global__ __launch_bounds__(256) void epilogue(
    const bf16* __restrict__ G, const float* __restrict__ c_prev,
    const float* __restrict__ bg, const float* __restrict__ bc,
    const float* __restrict__ W1, const float* __restrict__ b1,
    const float* __restrict__ W2, const float* __restrict__ b2,
    float* __restrict__ h_next, float* __restrict__ c_next) {
  int idx = blockIdx.x * 256 + threadIdx.x;   // one per (b,h)
  int b = idx >> 10;
  int h = idx & (HH - 1);
  const bf16* Gr = G + (size_t)b * NG;

  float gi = (float)Gr[h]          + bg[h];
  float gf = (float)Gr[HH + h]     + bg[HH + h];
  float go = (float)Gr[2 * HH + h] + bg[2 * HH + h];
  float p0 = (float)Gr[3 * HH + 2 * h]     + bc[2 * h];
  float p1 = (float)Gr[3 * HH + 2 * h + 1] + bc[2 * h + 1];

  float g = b2[0];
#pragma unroll
  for (int k = 0; k < KH; ++k) {
    float hv = fmaf(p0, W1[2 * k], fmaf(p1, W1[2 * k + 1], b1[k]));
    hv = fmaxf(hv, 0.0f);
    g = fmaf(hv, W2[k], g);
  }

  float si = 1.0f / (1.0f + __expf(-gi));
  float sf = 1.0f / (1.0f + __expf(-gf));
  float so = 1.0f / (1.0f + __expf(-go));

  float cn = sf * c_prev[idx] + si * g;
  float hn = so * tanhf(cn);
  h_next[idx] = hn;
  c_next[idx] = cn;
}

// ---------------------------------------------------------------------------
extern "C" void kernel_launch(void* const* d_in, const int* in_sizes, int n_in,
                              void* d_out, int out_size, void* d_ws, size_t ws_size,
                              hipStream_t stream) {
  const float* x      = (const float*)d_in[0];
  const float* h_prev = (const float*)d_in[1];
  const float* c_prev = (const float*)d_in[2];
  const float* Wg     = (const float*)d_in[3];
  const float* bg     = (const float*)d_in[4];
  const float* Wc     = (const float*)d_in[5];
  const float* bc     = (const float*)d_in[6];
  const float* W1     = (const float*)d_in[7];
  const float* b1     = (const float*)d_in[8];
  const float* W2     = (const float*)d_in[9];
  const float* b2     = (const float*)d_in[10];
  float* out = (float*)d_out;

  // workspace layout
  char* ws = (char*)d_ws;
  bf16* comb = (bf16*)ws;                                    // 16 MB
  bf16* Wb   = (bf16*)(ws + (size_t)BB * KIN * 2);           // 20 MB
  bf16* G    = (bf16*)(ws + (size_t)BB * KIN * 2
                          + (size_t)NG * KIN * 2);           // 40 MB

  // 1. prep (concat + casts + B fragment shuffle, one kernel)
  prep<<<(NC4 + NW8 + 255) / 256, 256, 0, stream>>>(x, h_prev, Wg, Wc, comb, Wb);

  // 2. GEMM
  dim3 grid(BB / 128, NG / 128);
  gemm_bt<<<grid, 256, 0, stream>>>(comb, Wb, G);

  // 3. epilogue
  epilogue<<<(BB * HH) / 256, 256, 0, stream>>>(
      G, c_prev, bg, bc, W1, b1, W2, b2, out, out + (size_t)BB * HH);
}